// Round 8
// baseline (280.990 us; speedup 1.0000x reference)
//
#include <hip/hip_runtime.h>

// Problem constants
#define B_  2
#define S_  2048
#define D_  1024
#define H_  16
#define DK_ 64

typedef __bf16 bf16;
typedef __bf16 bf16x8 __attribute__((ext_vector_type(8)));
typedef __bf16 bf16x4 __attribute__((ext_vector_type(4)));
typedef float  f32x4  __attribute__((ext_vector_type(4)));

#define GLD16(gptr, lptr) __builtin_amdgcn_global_load_lds( \
    (const __attribute__((address_space(1))) void*)(gptr),  \
    (__attribute__((address_space(3))) void*)(lptr), 16, 0, 0)

// ---------------------------------------------------------------------------
// Fused Q/K/V projection reading FP32 inputs directly (cast_all eliminated).
// Tile 128x64, BK=32, grid (512,3) = 6 blocks/CU. LDS 24KB (fp32 tiles).
// fp32 LDS swizzle: row = 32 floats = 4 x 32B superblocks; phys 16B-block
// p = (sb ^ (row&3))*2 + (half ^ ((row>>2)&1))  -> ~2-way max on frag reads.
// z=0: Qh = (q Wq^T + b)*sc2 (pre-scaled), head-split [B,H,S,64]
// z=1: Kh = k Wk^T + b, head-split;  z=2: Vt = Wv v^T + b(row), [D, B*S]
// ---------------------------------------------------------------------------
__global__ __launch_bounds__(256, 6) void gemm_qkv(
    const float* __restrict__ qf, const float* __restrict__ kf, const float* __restrict__ vf,
    const float* __restrict__ wqf, const float* __restrict__ wkf, const float* __restrict__ wvf,
    const float* __restrict__ biq, const float* __restrict__ bik, const float* __restrict__ biv,
    bf16* __restrict__ Qh, bf16* __restrict__ Kh, bf16* __restrict__ Vt) {
  __shared__ float Asf[128 * 32];   // 16 KB
  __shared__ float Bsf[64 * 32];    // 8 KB
  const int z = blockIdx.y;
  const float *A, *Bm, *bias; bf16* Cout;
  int bx, by, N;
  if (z == 0)      { A = qf;  Bm = wqf; bias = biq; Cout = Qh; }
  else if (z == 1) { A = kf;  Bm = wkf; bias = bik; Cout = Kh; }
  else             { A = wvf; Bm = vf;  bias = biv; Cout = Vt; }
  if (z < 2) { by = blockIdx.x & 31; bx = blockIdx.x >> 5; N = D_; }
  else       { bx = blockIdx.x & 63; by = blockIdx.x >> 6; N = B_ * S_; }
  const int K = D_;

  const int tid  = threadIdx.x;
  const int wave = tid >> 6, lane = tid & 63;
  const int g = lane >> 4, r = lane & 15;
  const int m0 = by * 128, n0 = bx * 64;

  f32x4 acc[2][4] = {};
  const int srow = tid >> 3;  // 0..31 (row within a 32-row staging pass)
  const int p    = tid & 7;   // phys 16B block within 128B row

  for (int k0 = 0; k0 < K; k0 += 32) {
    __syncthreads();
#pragma unroll
    for (int rep = 0; rep < 4; rep++) {      // A: 128 rows fp32
      int row = rep * 32 + srow;
      int sb = (p >> 1) ^ (row & 3);
      int hf = (p & 1) ^ ((row >> 2) & 1);
      GLD16(A + (size_t)(m0 + row) * K + k0 + sb * 8 + hf * 4,
            Asf + (rep * 32 + wave * 8) * 32);
    }
#pragma unroll
    for (int rep = 0; rep < 2; rep++) {      // B: 64 rows fp32
      int row = rep * 32 + srow;
      int sb = (p >> 1) ^ (row & 3);
      int hf = (p & 1) ^ ((row >> 2) & 1);
      GLD16(Bm + (size_t)(n0 + row) * K + k0 + sb * 8 + hf * 4,
            Bsf + (rep * 32 + wave * 8) * 32);
    }
    __syncthreads();

    // build bf16 fragments from fp32 LDS
    bf16x8 af[2], bfr[4];
#pragma unroll
    for (int i = 0; i < 2; i++) {
      int row = wave * 32 + i * 16 + r;
      int s = g ^ (row & 3), h0 = (row >> 2) & 1;
      float4 lo = *(const float4*)(Asf + row * 32 + (s * 2 + h0) * 4);
      float4 hi = *(const float4*)(Asf + row * 32 + (s * 2 + (h0 ^ 1)) * 4);
      bf16x8 o;
      o[0]=(bf16)lo.x; o[1]=(bf16)lo.y; o[2]=(bf16)lo.z; o[3]=(bf16)lo.w;
      o[4]=(bf16)hi.x; o[5]=(bf16)hi.y; o[6]=(bf16)hi.z; o[7]=(bf16)hi.w;
      af[i] = o;
    }
#pragma unroll
    for (int j = 0; j < 4; j++) {
      int row = j * 16 + r;
      int s = g ^ (row & 3), h0 = (row >> 2) & 1;
      float4 lo = *(const float4*)(Bsf + row * 32 + (s * 2 + h0) * 4);
      float4 hi = *(const float4*)(Bsf + row * 32 + (s * 2 + (h0 ^ 1)) * 4);
      bf16x8 o;
      o[0]=(bf16)lo.x; o[1]=(bf16)lo.y; o[2]=(bf16)lo.z; o[3]=(bf16)lo.w;
      o[4]=(bf16)hi.x; o[5]=(bf16)hi.y; o[6]=(bf16)hi.z; o[7]=(bf16)hi.w;
      bfr[j] = o;
    }
#pragma unroll
    for (int i = 0; i < 2; i++)
#pragma unroll
      for (int j = 0; j < 4; j++)
        acc[i][j] = __builtin_amdgcn_mfma_f32_16x16x32_bf16(af[i], bfr[j], acc[i][j], 0, 0, 0);
  }

  const float qscale = 0.18033688f;  // (1/sqrt(64)) * log2(e), folded into Q
#pragma unroll
  for (int i = 0; i < 2; i++) {
#pragma unroll
    for (int j = 0; j < 4; j++) {
#pragma unroll
      for (int t = 0; t < 4; t++) {
        int mrow = m0 + wave * 32 + i * 16 + g * 4 + t;
        int col  = n0 + j * 16 + r;
        float val = acc[i][j][t];
        if (z < 2) {
          val += bias[col];
          if (z == 0) val *= qscale;
          int bb2 = mrow >> 11, s = mrow & (S_ - 1);
          int hh = col >> 6, d = col & 63;
          Cout[(((size_t)(bb2 * H_ + hh)) * S_ + s) * 64 + d] = (bf16)val;
        } else {
          val += bias[mrow];
          Cout[(size_t)mrow * N + col] = (bf16)val;
        }
      }
    }
  }
}

// ---------------------------------------------------------------------------
// Flash attention — r7 config (unchanged): 2-way key split, grid 1024,
// 4 blocks/CU, XCD swizzle, chunked Ps, pre-scaled Q.
// ---------------------------------------------------------------------------
__global__ __launch_bounds__(256, 4) void flash_attn(const bf16* __restrict__ Qh,
                                                     const bf16* __restrict__ Kh,
                                                     const bf16* __restrict__ Vt,
                                                     bf16* __restrict__ Apart,
                                                     float* __restrict__ Lpart) {
  __shared__ bf16 Ks[64 * 64];    // 8 KB
  __shared__ bf16 Vs[64 * 64];    // 8 KB
  __shared__ bf16 Ps[128 * 40];   // 10 KB, one 32-key chunk, stride 40

  const int tid  = threadIdx.x;
  const int wave = tid >> 6, lane = tid & 63;
  const int g = lane >> 4, r = lane & 15;

  int qt = blockIdx.x >> 6;          // 0..15
  int kh = blockIdx.x & 1;           // 0..1
  int bh = (blockIdx.x >> 1) & 31;   // 0..31
  int h = bh & (H_ - 1), b = bh >> 4;

  const bf16* Kbase = Kh + ((size_t)bh * S_ + kh * 1024) * DK_;
  const bf16* Vbase = Vt + (size_t)h * 64 * (B_ * S_) + (size_t)b * S_ + kh * 1024;

  bf16x8 bq[2][2];
#pragma unroll
  for (int sq = 0; sq < 2; sq++) {
    int qrow = qt * 128 + wave * 32 + sq * 16 + r;
    const bf16* qp = Qh + ((size_t)bh * S_ + qrow) * DK_;
#pragma unroll
    for (int kc = 0; kc < 2; kc++)
      bq[sq][kc] = *(const bf16x8*)(qp + kc * 32 + g * 8);
  }

  f32x4 acc_o[2][4] = {};
  float l_run[2] = {0.f, 0.f};

  const int srow = tid >> 3, spp = tid & 7;

  for (int j0 = 0; j0 < 1024 / 64; j0++) {
    __syncthreads();
#pragma unroll
    for (int rep = 0; rep < 2; rep++) {
      int rr = rep * 32 + srow;
      int bb = spp ^ (rr & 7);
      GLD16(Kbase + (size_t)(j0 * 64 + rr) * 64 + bb * 8, Ks + rep * 2048 + wave * 512);
      GLD16(Vbase + (size_t)rr * (B_ * S_) + j0 * 64 + bb * 8, Vs + rep * 2048 + wave * 512);
    }
    __syncthreads();

    bf16x8 ak[4][2];
#pragma unroll
    for (int ks = 0; ks < 4; ks++) {
      int kr = ks * 16 + r;
#pragma unroll
      for (int kc = 0; kc < 2; kc++)
        ak[ks][kc] = *(const bf16x8*)(Ks + kr * 64 + (((kc * 4 + g) ^ (kr & 7)) * 8));
    }
    f32x4 sacc[2][4] = {};
#pragma unroll
    for (int sq = 0; sq < 2; sq++)
#pragma unroll
      for (int ks = 0; ks < 4; ks++)
#pragma unroll
        for (int kc = 0; kc < 2; kc++)
          sacc[sq][ks] = __builtin_amdgcn_mfma_f32_16x16x32_bf16(ak[ks][kc], bq[sq][kc],
                                                                 sacc[sq][ks], 0, 0, 0);

#pragma unroll
    for (int c = 0; c < 2; c++) {
#pragma unroll
      for (int sq = 0; sq < 2; sq++) {
        int qrow = wave * 32 + sq * 16 + r;
        float rs = 0.f;
#pragma unroll
        for (int k2 = 0; k2 < 2; k2++) {
          int ks = c * 2 + k2;
          bf16x4 pk;
#pragma unroll
          for (int t = 0; t < 4; t++) {
            float pv = __builtin_amdgcn_exp2f(sacc[sq][ks][t]);
            rs += pv;
            pk[t] = (bf16)pv;
          }
          *(bf16x4*)(Ps + qrow * 40 + k2 * 16 + g * 4) = pk;
        }
        l_run[sq] += rs;
      }
      asm volatile("s_waitcnt lgkmcnt(0)" ::: "memory");

      bf16x8 bp[2];
#pragma unroll
      for (int sq = 0; sq < 2; sq++) {
        int qrow = wave * 32 + sq * 16 + r;
        bp[sq] = *(const bf16x8*)(Ps + qrow * 40 + g * 8);
      }
#pragma unroll
      for (int dsub = 0; dsub < 4; dsub++) {
        int dr = dsub * 16 + r;
        bf16x8 av = *(const bf16x8*)(Vs + dr * 64 + (((c * 4 + g) ^ (dr & 7)) * 8));
#pragma unroll
        for (int sq = 0; sq < 2; sq++)
          acc_o[sq][dsub] = __builtin_amdgcn_mfma_f32_16x16x32_bf16(av, bp[sq],
                                                                    acc_o[sq][dsub], 0, 0, 0);
      }
    }
  }

#pragma unroll
  for (int sq = 0; sq < 2; sq++) {
    float l = l_run[sq];
    l += __shfl_xor(l, 16, 64);
    l += __shfl_xor(l, 32, 64);
    int s = qt * 128 + wave * 32 + sq * 16 + r;
    if (g == 0)
      Lpart[(size_t)kh * (B_ * H_ * S_) + (size_t)bh * S_ + s] = l;
    size_t base = (size_t)kh * (B_ * S_ * (size_t)D_) + ((size_t)b * S_ + s) * D_ + (size_t)h * 64;
#pragma unroll
    for (int dsub = 0; dsub < 4; dsub++) {
      bf16x4 o;
#pragma unroll
      for (int t = 0; t < 4; t++) o[t] = (bf16)(acc_o[sq][dsub][t]);
      *(bf16x4*)(Apart + base + dsub * 16 + g * 4) = o;
    }
  }
}

// ---------------------------------------------------------------------------
// Final projection with FUSED combine: out[m,n] = sum_k ((A0+A1)[m,k] *
// invl[m, k>>6]) * Wo[n,k] + b[n]. Normalizer is per K-column HEAD, so it is
// applied at fragment build (BK=32 => head uniform per K-iter). Wo read fp32.
// Tile 128x64, grid 512 (by-grouped for XCD/L2). LDS 32 KB.
// ---------------------------------------------------------------------------
__global__ __launch_bounds__(256) void gemm_out(const bf16* __restrict__ A0,
                                                const bf16* __restrict__ A1,
                                                const float* __restrict__ Wo,
                                                const float* __restrict__ Lpart,
                                                const float* __restrict__ bias,
                                                float* __restrict__ Cout) {
  __shared__ bf16  As0[128 * 32];   // 8 KB
  __shared__ bf16  As1[128 * 32];   // 8 KB
  __shared__ float Bsf[64 * 32];    // 8 KB (fp32 Wo tile)
  __shared__ float invl[128 * 16];  // 8 KB: 1/(l0+l1) per (tile-row, head)
  const int K = D_, N = D_;
  const int tid  = threadIdx.x;
  const int wave = tid >> 6, lane = tid & 63;
  const int g = lane >> 4, r = lane & 15;
  const int by = blockIdx.x & 31, bx = blockIdx.x >> 5;
  const int m0 = by * 128, n0 = bx * 64;
  const int LHALF = B_ * H_ * S_;

  // precompute invl (covered by the K-loop's first __syncthreads)
  for (int e = tid; e < 128 * 16; e += 256) {
    int row = e >> 4, hh = e & 15;
    int m = m0 + row;
    int li = ((m >> 11) * H_ + hh) * S_ + (m & (S_ - 1));
    invl[e] = 1.0f / (Lpart[li] + Lpart[li + LHALF]);
  }

  f32x4 acc[2][4] = {};
  const int srowA = tid >> 2, spA = tid & 3;   // bf16 tiles (64B rows)
  const int srowB = tid >> 3, pB  = tid & 7;   // fp32 tile (128B rows)

  for (int k0 = 0; k0 < K; k0 += 32) {
    __syncthreads();
#pragma unroll
    for (int rep = 0; rep < 2; rep++) {
      int row = rep * 64 + srowA;
      int bb  = spA ^ ((row >> 1) & 3);
      GLD16(A0 + (size_t)(m0 + row) * K + k0 + bb * 8, As0 + (rep * 256 + wave * 64) * 8);
      GLD16(A1 + (size_t)(m0 + row) * K + k0 + bb * 8, As1 + (rep * 256 + wave * 64) * 8);
    }
#pragma unroll
    for (int rep = 0; rep < 2; rep++) {
      int row = rep * 32 + srowB;
      int sb = (pB >> 1) ^ (row & 3);
      int hf = (pB & 1) ^ ((row >> 2) & 1);
      GLD16(Wo + (size_t)(n0 + row) * K + k0 + sb * 8 + hf * 4,
            Bsf + (rep * 32 + wave * 8) * 32);
    }
    __syncthreads();

    const int head = k0 >> 6;
    bf16x8 af[2], bfr[4];
#pragma unroll
    for (int i = 0; i < 2; i++) {
      int row = wave * 32 + i * 16 + r;
      bf16x8 a0 = *(const bf16x8*)(As0 + row * 32 + (g ^ ((row >> 1) & 3)) * 8);
      bf16x8 a1 = *(const bf16x8*)(As1 + row * 32 + (g ^ ((row >> 1) & 3)) * 8);
      float sc = invl[row * 16 + head];
      bf16x8 o;
#pragma unroll
      for (int t = 0; t < 8; t++) o[t] = (bf16)(((float)a0[t] + (float)a1[t]) * sc);
      af[i] = o;
    }
#pragma unroll
    for (int j = 0; j < 4; j++) {
      int row = j * 16 + r;
      int s = g ^ (row & 3), h0 = (row >> 2) & 1;
      float4 lo = *(const float4*)(Bsf + row * 32 + (s * 2 + h0) * 4);
      float4 hi = *(const float4*)(Bsf + row * 32 + (s * 2 + (h0 ^ 1)) * 4);
      bf16x8 o;
      o[0]=(bf16)lo.x; o[1]=(bf16)lo.y; o[2]=(bf16)lo.z; o[3]=(bf16)lo.w;
      o[4]=(bf16)hi.x; o[5]=(bf16)hi.y; o[6]=(bf16)hi.z; o[7]=(bf16)hi.w;
      bfr[j] = o;
    }
#pragma unroll
    for (int i = 0; i < 2; i++)
#pragma unroll
      for (int j = 0; j < 4; j++)
        acc[i][j] = __builtin_amdgcn_mfma_f32_16x16x32_bf16(af[i], bfr[j], acc[i][j], 0, 0, 0);
  }

#pragma unroll
  for (int i = 0; i < 2; i++)
#pragma unroll
    for (int j = 0; j < 4; j++)
#pragma unroll
      for (int t = 0; t < 4; t++) {
        int mrow = m0 + wave * 32 + i * 16 + g * 4 + t;
        int col  = n0 + j * 16 + r;
        Cout[(size_t)mrow * N + col] = acc[i][j][t] + bias[col];
      }
}

// ---------------------------------------------------------------------------
extern "C" void kernel_launch(void* const* d_in, const int* in_sizes, int n_in,
                              void* d_out, int out_size, void* d_ws, size_t ws_size,
                              hipStream_t stream) {
  const float* q    = (const float*)d_in[0];
  const float* k    = (const float*)d_in[1];
  const float* v    = (const float*)d_in[2];
  const float* wq_w = (const float*)d_in[3];
  const float* wq_b = (const float*)d_in[4];
  const float* wk_w = (const float*)d_in[5];
  const float* wk_b = (const float*)d_in[6];
  const float* wv_w = (const float*)d_in[7];
  const float* wv_b = (const float*)d_in[8];
  const float* wo_w = (const float*)d_in[9];
  const float* wo_b = (const float*)d_in[10];

  bf16* W = (bf16*)d_ws;
  const size_t NTOK = (size_t)B_ * S_;   // 4096
  const size_t EQ = NTOK * D_;
  bf16* Qhb   = W;                 // [B,H,S,64], pre-scaled
  bf16* Khb   = Qhb + EQ;          // [B,H,S,64]
  bf16* Vtb   = Khb + EQ;          // [H,64,B,S]
  bf16* Apart = Vtb + EQ;          // 2 contiguous halves, 16 MB
  float* Lpart = (float*)(Apart + 2 * EQ);  // 2 x B*H*S fp32 (512 KB)
  // total ~40.5 MB of 64 MB ws

  gemm_qkv<<<dim3(512, 3), 256, 0, stream>>>(q, k, v, wq_w, wk_w, wv_w,
                                             wq_b, wk_b, wv_b, Qhb, Khb, Vtb);

  flash_attn<<<1024, 256, 0, stream>>>(Qhb, Khb, Vtb, Apart, Lpart);

  gemm_out<<<512, 256, 0, stream>>>(Apart, Apart + EQ, wo_w, Lpart, wo_b, (float*)d_out);
}

// Round 9
// 224.251 us; speedup vs baseline: 1.2530x; 1.2530x over previous
//
#include <hip/hip_runtime.h>

// Problem constants
#define B_  2
#define S_  2048
#define D_  1024
#define H_  16
#define DK_ 64

typedef __bf16 bf16;
typedef __bf16 bf16x8 __attribute__((ext_vector_type(8)));
typedef __bf16 bf16x4 __attribute__((ext_vector_type(4)));
typedef float  f32x4  __attribute__((ext_vector_type(4)));

#define GLD16(gptr, lptr) __builtin_amdgcn_global_load_lds( \
    (const __attribute__((address_space(1))) void*)(gptr),  \
    (__attribute__((address_space(3))) void*)(lptr), 16, 0, 0)

// ---------------------------------------------------------------------------
// fused fp32 -> bf16 cast for all 7 tensors in ONE launch (2048 elems/block)
// (r8 lesson: keep staging dtype = compute dtype; fp32-direct GEMM staging
// doubled FETCH and added per-iter cvt VALU — qkv 51->94us.)
// ---------------------------------------------------------------------------
__global__ __launch_bounds__(256) void cast_all(
    const float* __restrict__ q, const float* __restrict__ k, const float* __restrict__ v,
    const float* __restrict__ wq, const float* __restrict__ wk, const float* __restrict__ wv,
    const float* __restrict__ wo,
    bf16* __restrict__ qb, bf16* __restrict__ kb, bf16* __restrict__ vb,
    bf16* __restrict__ wqb, bf16* __restrict__ wkb, bf16* __restrict__ wvb,
    bf16* __restrict__ wob) {
  int blk = blockIdx.x;
  const float* in; bf16* out; int base;
  if      (blk < 2048) { in = q;  out = qb;  base = blk; }
  else if (blk < 4096) { in = k;  out = kb;  base = blk - 2048; }
  else if (blk < 6144) { in = v;  out = vb;  base = blk - 4096; }
  else if (blk < 6656) { in = wq; out = wqb; base = blk - 6144; }
  else if (blk < 7168) { in = wk; out = wkb; base = blk - 6656; }
  else if (blk < 7680) { in = wv; out = wvb; base = blk - 7168; }
  else                 { in = wo; out = wob; base = blk - 7680; }
  int i = (base * 256 + threadIdx.x) * 8;
  float4 a = *(const float4*)(in + i);
  float4 b = *(const float4*)(in + i + 4);
  bf16x8 o;
  o[0] = (bf16)a.x; o[1] = (bf16)a.y; o[2] = (bf16)a.z; o[3] = (bf16)a.w;
  o[4] = (bf16)b.x; o[5] = (bf16)b.y; o[6] = (bf16)b.z; o[7] = (bf16)b.w;
  *(bf16x8*)(out + i) = o;
}

// ---------------------------------------------------------------------------
// Fused Q/K/V projection. Tile 128x64, BK=64 -> 16 K-iters (half of r7's 32
// barrier drains) at UNCHANGED 6 blocks/CU (LDS 24KB). grid (512,3).
// XCD swizzle: z<2 same-by stride 32 (same %8 -> same XCD); z=2 same-bx.
// z=0: Qh = (q Wq^T + b)*sc2 (pre-scaled), head-split [B,H,S,64]
// z=1: Kh = k Wk^T + b, head-split;  z=2: Vt = Wv v^T + b(row), [D, B*S]
// ---------------------------------------------------------------------------
__global__ __launch_bounds__(256, 6) void gemm_qkv(
    const bf16* __restrict__ qb, const bf16* __restrict__ kb, const bf16* __restrict__ vb,
    const bf16* __restrict__ wq, const bf16* __restrict__ wk, const bf16* __restrict__ wv,
    const float* __restrict__ biq, const float* __restrict__ bik, const float* __restrict__ biv,
    bf16* __restrict__ Qh, bf16* __restrict__ Kh, bf16* __restrict__ Vt) {
  __shared__ bf16 As[128 * 64];   // 16 KB
  __shared__ bf16 Bs[64 * 64];    // 8 KB
  const int z = blockIdx.y;
  const bf16 *A, *Bm; const float* bias; bf16* Cout;
  int bx, by, N;
  if (z == 0)      { A = qb; Bm = wq; bias = biq; Cout = Qh; }
  else if (z == 1) { A = kb; Bm = wk; bias = bik; Cout = Kh; }
  else             { A = wv; Bm = vb; bias = biv; Cout = Vt; }
  if (z < 2) { by = blockIdx.x & 31; bx = blockIdx.x >> 5; N = D_; }
  else       { bx = blockIdx.x & 63; by = blockIdx.x >> 6; N = B_ * S_; }
  const int K = D_;

  const int tid  = threadIdx.x;
  const int wave = tid >> 6, lane = tid & 63;
  const int g = lane >> 4, r = lane & 15;
  const int m0 = by * 128, n0 = bx * 64;

  f32x4 acc[2][4] = {};
  const int srow = tid >> 3;  // 0..31
  const int sp   = tid & 7;   // 16B block in 128B row

  for (int k0 = 0; k0 < K; k0 += 64) {
    __syncthreads();
#pragma unroll
    for (int rep = 0; rep < 4; rep++) {       // A: 128 rows
      int row = rep * 32 + srow;
      int bb  = sp ^ (row & 7);
      GLD16(A + (size_t)(m0 + row) * K + k0 + bb * 8, As + rep * 2048 + wave * 512);
    }
#pragma unroll
    for (int rep = 0; rep < 2; rep++) {       // B: 64 rows
      int row = rep * 32 + srow;
      int bb  = sp ^ (row & 7);
      GLD16(Bm + (size_t)(n0 + row) * K + k0 + bb * 8, Bs + rep * 2048 + wave * 512);
    }
    __syncthreads();

#pragma unroll
    for (int kc = 0; kc < 2; kc++) {
      bf16x8 af[2], bfr[4];
#pragma unroll
      for (int i = 0; i < 2; i++) {
        int row = wave * 32 + i * 16 + r;
        af[i] = *(const bf16x8*)(As + row * 64 + (((kc * 4 + g) ^ (row & 7)) * 8));
      }
#pragma unroll
      for (int j = 0; j < 4; j++) {
        int row = j * 16 + r;
        bfr[j] = *(const bf16x8*)(Bs + row * 64 + (((kc * 4 + g) ^ (row & 7)) * 8));
      }
#pragma unroll
      for (int i = 0; i < 2; i++)
#pragma unroll
        for (int j = 0; j < 4; j++)
          acc[i][j] = __builtin_amdgcn_mfma_f32_16x16x32_bf16(af[i], bfr[j], acc[i][j], 0, 0, 0);
    }
  }

  const float qscale = 0.18033688f;  // (1/sqrt(64)) * log2(e), folded into Q
#pragma unroll
  for (int i = 0; i < 2; i++) {
#pragma unroll
    for (int j = 0; j < 4; j++) {
#pragma unroll
      for (int t = 0; t < 4; t++) {
        int mrow = m0 + wave * 32 + i * 16 + g * 4 + t;
        int col  = n0 + j * 16 + r;
        float val = acc[i][j][t];
        if (z < 2) {
          val += bias[col];
          if (z == 0) val *= qscale;
          int bb2 = mrow >> 11, s = mrow & (S_ - 1);
          int hh = col >> 6, d = col & 63;
          Cout[(((size_t)(bb2 * H_ + hh)) * S_ + s) * 64 + d] = (bf16)val;
        } else {
          val += bias[mrow];
          Cout[(size_t)mrow * N + col] = (bf16)val;
        }
      }
    }
  }
}

// ---------------------------------------------------------------------------
// Final projection: out = AO Wo^T + b (fp32). Tile 128x64, BK=64, 6 blocks/CU.
// XCD grouping: same-bx blocks stride 16 -> same %8 -> Wo tile hot in one L2.
// ---------------------------------------------------------------------------
__global__ __launch_bounds__(256, 6) void gemm_out(const bf16* __restrict__ A,
                                                   const bf16* __restrict__ Bm,
                                                   const float* __restrict__ bias,
                                                   float* __restrict__ Cout) {
  __shared__ bf16 As[128 * 64];   // 16 KB
  __shared__ bf16 Bs[64 * 64];    // 8 KB
  const int K = D_, N = D_;
  const int tid  = threadIdx.x;
  const int wave = tid >> 6, lane = tid & 63;
  const int g = lane >> 4, r = lane & 15;
  const int bx = blockIdx.x & 15, by = blockIdx.x >> 4;
  const int m0 = by * 128, n0 = bx * 64;

  f32x4 acc[2][4] = {};
  const int srow = tid >> 3;
  const int sp   = tid & 7;

  for (int k0 = 0; k0 < K; k0 += 64) {
    __syncthreads();
#pragma unroll
    for (int rep = 0; rep < 4; rep++) {
      int row = rep * 32 + srow;
      int bb  = sp ^ (row & 7);
      GLD16(A + (size_t)(m0 + row) * K + k0 + bb * 8, As + rep * 2048 + wave * 512);
    }
#pragma unroll
    for (int rep = 0; rep < 2; rep++) {
      int row = rep * 32 + srow;
      int bb  = sp ^ (row & 7);
      GLD16(Bm + (size_t)(n0 + row) * K + k0 + bb * 8, Bs + rep * 2048 + wave * 512);
    }
    __syncthreads();

#pragma unroll
    for (int kc = 0; kc < 2; kc++) {
      bf16x8 af[2], bfr[4];
#pragma unroll
      for (int i = 0; i < 2; i++) {
        int row = wave * 32 + i * 16 + r;
        af[i] = *(const bf16x8*)(As + row * 64 + (((kc * 4 + g) ^ (row & 7)) * 8));
      }
#pragma unroll
      for (int j = 0; j < 4; j++) {
        int row = j * 16 + r;
        bfr[j] = *(const bf16x8*)(Bs + row * 64 + (((kc * 4 + g) ^ (row & 7)) * 8));
      }
#pragma unroll
      for (int i = 0; i < 2; i++)
#pragma unroll
        for (int j = 0; j < 4; j++)
          acc[i][j] = __builtin_amdgcn_mfma_f32_16x16x32_bf16(af[i], bfr[j], acc[i][j], 0, 0, 0);
    }
  }

#pragma unroll
  for (int i = 0; i < 2; i++)
#pragma unroll
    for (int j = 0; j < 4; j++)
#pragma unroll
      for (int t = 0; t < 4; t++) {
        int mrow = m0 + wave * 32 + i * 16 + g * 4 + t;
        int col  = n0 + j * 16 + r;
        Cout[(size_t)mrow * N + col] = acc[i][j][t] + bias[col];
      }
}

// ---------------------------------------------------------------------------
// Flash attention — r7 config (unchanged): 2-way key split, grid 1024,
// 4 blocks/CU, XCD swizzle, chunked Ps, pre-scaled Q.
// ---------------------------------------------------------------------------
__global__ __launch_bounds__(256, 4) void flash_attn(const bf16* __restrict__ Qh,
                                                     const bf16* __restrict__ Kh,
                                                     const bf16* __restrict__ Vt,
                                                     bf16* __restrict__ Apart,
                                                     float* __restrict__ Lpart) {
  __shared__ bf16 Ks[64 * 64];    // 8 KB
  __shared__ bf16 Vs[64 * 64];    // 8 KB
  __shared__ bf16 Ps[128 * 40];   // 10 KB, one 32-key chunk, stride 40

  const int tid  = threadIdx.x;
  const int wave = tid >> 6, lane = tid & 63;
  const int g = lane >> 4, r = lane & 15;

  int qt = blockIdx.x >> 6;          // 0..15
  int kh = blockIdx.x & 1;           // 0..1
  int bh = (blockIdx.x >> 1) & 31;   // 0..31
  int h = bh & (H_ - 1), b = bh >> 4;

  const bf16* Kbase = Kh + ((size_t)bh * S_ + kh * 1024) * DK_;
  const bf16* Vbase = Vt + (size_t)h * 64 * (B_ * S_) + (size_t)b * S_ + kh * 1024;

  bf16x8 bq[2][2];
#pragma unroll
  for (int sq = 0; sq < 2; sq++) {
    int qrow = qt * 128 + wave * 32 + sq * 16 + r;
    const bf16* qp = Qh + ((size_t)bh * S_ + qrow) * DK_;
#pragma unroll
    for (int kc = 0; kc < 2; kc++)
      bq[sq][kc] = *(const bf16x8*)(qp + kc * 32 + g * 8);
  }

  f32x4 acc_o[2][4] = {};
  float l_run[2] = {0.f, 0.f};

  const int srow = tid >> 3, spp = tid & 7;

  for (int j0 = 0; j0 < 1024 / 64; j0++) {
    __syncthreads();
#pragma unroll
    for (int rep = 0; rep < 2; rep++) {
      int rr = rep * 32 + srow;
      int bb = spp ^ (rr & 7);
      GLD16(Kbase + (size_t)(j0 * 64 + rr) * 64 + bb * 8, Ks + rep * 2048 + wave * 512);
      GLD16(Vbase + (size_t)rr * (B_ * S_) + j0 * 64 + bb * 8, Vs + rep * 2048 + wave * 512);
    }
    __syncthreads();

    bf16x8 ak[4][2];
#pragma unroll
    for (int ks = 0; ks < 4; ks++) {
      int kr = ks * 16 + r;
#pragma unroll
      for (int kc = 0; kc < 2; kc++)
        ak[ks][kc] = *(const bf16x8*)(Ks + kr * 64 + (((kc * 4 + g) ^ (kr & 7)) * 8));
    }
    f32x4 sacc[2][4] = {};
#pragma unroll
    for (int sq = 0; sq < 2; sq++)
#pragma unroll
      for (int ks = 0; ks < 4; ks++)
#pragma unroll
        for (int kc = 0; kc < 2; kc++)
          sacc[sq][ks] = __builtin_amdgcn_mfma_f32_16x16x32_bf16(ak[ks][kc], bq[sq][kc],
                                                                 sacc[sq][ks], 0, 0, 0);

#pragma unroll
    for (int c = 0; c < 2; c++) {
#pragma unroll
      for (int sq = 0; sq < 2; sq++) {
        int qrow = wave * 32 + sq * 16 + r;
        float rs = 0.f;
#pragma unroll
        for (int k2 = 0; k2 < 2; k2++) {
          int ks = c * 2 + k2;
          bf16x4 pk;
#pragma unroll
          for (int t = 0; t < 4; t++) {
            float pv = __builtin_amdgcn_exp2f(sacc[sq][ks][t]);
            rs += pv;
            pk[t] = (bf16)pv;
          }
          *(bf16x4*)(Ps + qrow * 40 + k2 * 16 + g * 4) = pk;
        }
        l_run[sq] += rs;
      }
      asm volatile("s_waitcnt lgkmcnt(0)" ::: "memory");

      bf16x8 bp[2];
#pragma unroll
      for (int sq = 0; sq < 2; sq++) {
        int qrow = wave * 32 + sq * 16 + r;
        bp[sq] = *(const bf16x8*)(Ps + qrow * 40 + g * 8);
      }
#pragma unroll
      for (int dsub = 0; dsub < 4; dsub++) {
        int dr = dsub * 16 + r;
        bf16x8 av = *(const bf16x8*)(Vs + dr * 64 + (((c * 4 + g) ^ (dr & 7)) * 8));
#pragma unroll
        for (int sq = 0; sq < 2; sq++)
          acc_o[sq][dsub] = __builtin_amdgcn_mfma_f32_16x16x32_bf16(av, bp[sq],
                                                                    acc_o[sq][dsub], 0, 0, 0);
      }
    }
  }

#pragma unroll
  for (int sq = 0; sq < 2; sq++) {
    float l = l_run[sq];
    l += __shfl_xor(l, 16, 64);
    l += __shfl_xor(l, 32, 64);
    int s = qt * 128 + wave * 32 + sq * 16 + r;
    if (g == 0)
      Lpart[(size_t)kh * (B_ * H_ * S_) + (size_t)bh * S_ + s] = l;
    size_t base = (size_t)kh * (B_ * S_ * (size_t)D_) + ((size_t)b * S_ + s) * D_ + (size_t)h * 64;
#pragma unroll
    for (int dsub = 0; dsub < 4; dsub++) {
      bf16x4 o;
#pragma unroll
      for (int t = 0; t < 4; t++) o[t] = (bf16)(acc_o[sq][dsub][t]);
      *(bf16x4*)(Apart + base + dsub * 16 + g * 4) = o;
    }
  }
}

// ---------------------------------------------------------------------------
// combine: AO = (A0 + A1) / (l0 + l1). 8 elems/thread.
// ---------------------------------------------------------------------------
__global__ __launch_bounds__(256) void combine(const bf16* __restrict__ Apart,
                                               const float* __restrict__ Lpart,
                                               bf16* __restrict__ AO) {
  const size_t EQ = (size_t)B_ * S_ * D_;
  const int LHALF = B_ * H_ * S_;
  int idx = (blockIdx.x * 256 + threadIdx.x) * 8;
  int token = idx >> 10;           // b*S + s
  int dcol  = idx & (D_ - 1);
  int b = token >> 11, s = token & (S_ - 1);
  int h = dcol >> 6;
  int li = (b * H_ + h) * S_ + s;
  float inv = 1.0f / (Lpart[li] + Lpart[li + LHALF]);
  bf16x8 a0 = *(const bf16x8*)(Apart + idx);
  bf16x8 a1 = *(const bf16x8*)(Apart + EQ + idx);
  bf16x8 o;
#pragma unroll
  for (int t = 0; t < 8; t++) o[t] = (bf16)(((float)a0[t] + (float)a1[t]) * inv);
  *(bf16x8*)(AO + idx) = o;
}

// ---------------------------------------------------------------------------
extern "C" void kernel_launch(void* const* d_in, const int* in_sizes, int n_in,
                              void* d_out, int out_size, void* d_ws, size_t ws_size,
                              hipStream_t stream) {
  const float* q    = (const float*)d_in[0];
  const float* k    = (const float*)d_in[1];
  const float* v    = (const float*)d_in[2];
  const float* wq_w = (const float*)d_in[3];
  const float* wq_b = (const float*)d_in[4];
  const float* wk_w = (const float*)d_in[5];
  const float* wk_b = (const float*)d_in[6];
  const float* wv_w = (const float*)d_in[7];
  const float* wv_b = (const float*)d_in[8];
  const float* wo_w = (const float*)d_in[9];
  const float* wo_b = (const float*)d_in[10];

  bf16* W = (bf16*)d_ws;
  const size_t NTOK = (size_t)B_ * S_;   // 4096
  const size_t EQ = NTOK * D_;
  const size_t EW = (size_t)D_ * D_;
  bf16* qb  = W;          // later reused: Apart (2 contiguous halves, 16MB)
  bf16* kb  = qb  + EQ;
  bf16* vb  = kb  + EQ;   // later reused: Lpart (fp32, 0.5MB)
  bf16* Qhb = vb  + EQ;   // [B,H,S,64], pre-scaled
  bf16* Khb = Qhb + EQ;   // [B,H,S,64]
  bf16* Vtb = Khb + EQ;   // [H,64,B,S]
  bf16* AOb = Vtb + EQ;   // [B,S,H*64]
  bf16* wqb = AOb + EQ;
  bf16* wkb = wqb + EW;
  bf16* wvb = wkb + EW;
  bf16* wob = wvb + EW;   // 64 MiB total

  bf16*  Apart = qb;           // 2 x EQ bf16 (overwrites dead qb/kb)
  float* Lpart = (float*)vb;   // 2 x B*H*S fp32 (overwrites dead vb)

  cast_all<<<8192, 256, 0, stream>>>(q, k, v, wq_w, wk_w, wv_w, wo_w,
                                     qb, kb, vb, wqb, wkb, wvb, wob);

  gemm_qkv<<<dim3(512, 3), 256, 0, stream>>>(qb, kb, vb, wqb, wkb, wvb,
                                             wq_b, wk_b, wv_b, Qhb, Khb, Vtb);

  flash_attn<<<1024, 256, 0, stream>>>(Qhb, Khb, Vtb, Apart, Lpart);

  combine<<<2048, 256, 0, stream>>>(Apart, Lpart, AOb);

  gemm_out<<<512, 256, 0, stream>>>(AOb, wob, wo_b, (float*)d_out);
}